// Round 11
// baseline (236.415 us; speedup 1.0000x reference)
//
#include <hip/hip_runtime.h>

#define N_USERS 100000
#define N_ITEMS 400000
#define N_NODES 500000
#define EMB_DIM 64
#define N_EDGES 1200000

#define BUCK_SHIFT 11
#define BUCK_NODES 2048                      // nodes per bucket
#define NBUCK 245                            // ceil(500000/2048)
#define BUCK_CAP 6144                        // >= max bucket count (mean ~4915, +17 sigma)
#define CHUNK 4096                           // edges per bsort block
#define NB_SORT 293                          // ceil(N_EDGES/CHUNK)
#define NB_CONV 1024                         // conv blocks appended to bsort grid

typedef long long ll;
typedef float f4 __attribute__((ext_vector_type(4)));
typedef float f8 __attribute__((ext_vector_type(8)));
typedef unsigned short u16;
typedef u16 us8 __attribute__((ext_vector_type(8)));   // 16 B (8 bf16)

__device__ __forceinline__ u16 f2bf(float f) {
    unsigned u = __float_as_uint(f);
    u += 0x7FFF + ((u >> 16) & 1);          // round-to-nearest-even
    return (u16)(u >> 16);
}
__device__ __forceinline__ float bf2f(u16 h) {
    return __uint_as_float(((unsigned)h) << 16);
}
__device__ __forceinline__ void fma8(f8& s, float w, us8 v) {
    #pragma unroll
    for (int k = 0; k < 8; ++k) s[k] += w * bf2f(v[k]);
}

// ---------------------------------------------------------------------------
// CSR build, locality-staged. bsort fused with x0->bf16 conversion.
// ---------------------------------------------------------------------------

__global__ void k_init(int* __restrict__ gcur) {
    if (threadIdx.x < 256) gcur[threadIdx.x] = 0;
}

__global__ void k_bsort_conv(const int* __restrict__ src, const int* __restrict__ dst,
                             const float* __restrict__ w,
                             int* __restrict__ gcur, uint2* __restrict__ stage,
                             const f4* __restrict__ u4, const f4* __restrict__ i4,
                             us8* __restrict__ x0b) {
    __shared__ int lhist[256];
    __shared__ int gbase_s[256];
    __shared__ int lcur[256];
    int tid = threadIdx.x;

    if (blockIdx.x >= NB_SORT) {
        // ---- conv portion: x0 fp32 -> bf16, streaming ----
        const int total = N_NODES * 8;       // us8 slots
        const int user8 = N_USERS * 8;
        int i0 = (blockIdx.x - NB_SORT) * 256 + tid;
        int stride = NB_CONV * 256;
        for (int i = i0; i < total; i += stride) {
            const f4* p = (i < user8) ? (u4 + (ll)i * 2) : (i4 + (ll)(i - user8) * 2);
            f4 lo = __builtin_nontemporal_load(p);
            f4 hi = __builtin_nontemporal_load(p + 1);
            us8 o;
            #pragma unroll
            for (int k = 0; k < 4; ++k) { o[k] = f2bf(lo[k]); o[k + 4] = f2bf(hi[k]); }
            x0b[i] = o;
        }
        return;
    }

    // ---- bsort portion ----
    lhist[tid] = 0;
    __syncthreads();
    int c0 = blockIdx.x * CHUNK;
    int c1 = c0 + CHUNK < N_EDGES ? c0 + CHUNK : N_EDGES;
    #pragma unroll
    for (int r = 0; r < CHUNK / 256; ++r) {
        int e = c0 + r * 256 + tid;
        if (e < c1) atomicAdd(&lhist[dst[e] >> BUCK_SHIFT], 1);
    }
    __syncthreads();
    if (tid < NBUCK) {
        gbase_s[tid] = atomicAdd(&gcur[tid], lhist[tid]);
        lcur[tid] = 0;
    }
    __syncthreads();
    #pragma unroll
    for (int r = 0; r < CHUNK / 256; ++r) {
        int e = c0 + r * 256 + tid;
        if (e < c1) {
            int s = src[e];
            int d = dst[e];
            float wt = w[e];
            int b = d >> BUCK_SHIFT;
            int k = atomicAdd(&lcur[b], 1);
            ll idx = (ll)b * BUCK_CAP + gbase_s[b] + k;
            stage[idx] = make_uint2((unsigned)s | ((unsigned)(d & (BUCK_NODES - 1)) << 19),
                                    __float_as_uint(wt));
        }
    }
}

// Exclusive scan of the 245 bucket totals (one block).
__global__ void k_bscan(const int* __restrict__ gcur, int* __restrict__ bbase,
                        int* __restrict__ rowptr) {
    __shared__ int tmp[256];
    int t = threadIdx.x;
    int v = (t < NBUCK) ? gcur[t] : 0;
    tmp[t] = v;
    __syncthreads();
    for (int off = 1; off < 256; off <<= 1) {
        int x = (t >= off) ? tmp[t - off] : 0;
        __syncthreads();
        tmp[t] += x;
        __syncthreads();
    }
    if (t < NBUCK) bbase[t] = tmp[t] - v;
    if (t == 0) rowptr[N_NODES] = N_EDGES;
}

// Per-bucket: LDS histogram -> LDS scan -> rowptr write -> place into CSR.
__global__ void k_place2(const uint2* __restrict__ stage, const int* __restrict__ gcur,
                         const int* __restrict__ bbase,
                         int* __restrict__ rowptr, int2* __restrict__ csr) {
    __shared__ int lh[BUCK_NODES];
    __shared__ int tsum[256];
    int b = blockIdx.x;
    int tid = threadIdx.x;
    #pragma unroll
    for (int r = 0; r < BUCK_NODES / 256; ++r) lh[r * 256 + tid] = 0;
    __syncthreads();
    int cnt = gcur[b];
    const uint2* sb = stage + (ll)b * BUCK_CAP;
    for (int i = tid; i < cnt; i += 256)
        atomicAdd(&lh[(sb[i].x >> 19) & (BUCK_NODES - 1)], 1);
    __syncthreads();
    // scan: thread t owns lh[t*8 .. t*8+7]
    int base_t = tid * 8;
    int v[8];
    int s = 0;
    #pragma unroll
    for (int k = 0; k < 8; ++k) { v[k] = lh[base_t + k]; s += v[k]; }
    tsum[tid] = s;
    __syncthreads();
    for (int off = 1; off < 256; off <<= 1) {
        int x = (tid >= off) ? tsum[tid - off] : 0;
        __syncthreads();
        tsum[tid] += x;
        __syncthreads();
    }
    int run = bbase[b] + tsum[tid] - s;       // absolute exclusive prefix
    int nbase = b * BUCK_NODES;
    #pragma unroll
    for (int k = 0; k < 8; ++k) {
        int i = base_t + k;
        int n = nbase + i;
        if (n < N_NODES) rowptr[n] = run;
        lh[i] = run;                          // absolute cursor
        run += v[k];
    }
    __syncthreads();
    for (int i = tid; i < cnt; i += 256) {
        uint2 e = sb[i];
        int ldst = (e.x >> 19) & (BUCK_NODES - 1);
        int pos = atomicAdd(&lh[ldst], 1);
        csr[pos] = make_int2((int)(e.x & 0x7FFFF), (int)e.y);
    }
}

// ---------------------------------------------------------------------------
// Propagation: 8 nodes/wave, 8 lanes x bf16x8 per node; batch-of-4 gathers.
// ---------------------------------------------------------------------------

__device__ __forceinline__ f8 gather8(const us8* __restrict__ xin,
                                      const int* __restrict__ rowptr,
                                      const int2* __restrict__ csr,
                                      int n, int fl) {
    int start = rowptr[n];
    int end   = rowptr[n + 1];
    int deg = end - start;
    f8 s = {0.f, 0.f, 0.f, 0.f, 0.f, 0.f, 0.f, 0.f};
    if (deg > 0) {
        int lastj = end - 1;
        int j1 = start + 1 < end ? start + 1 : lastj;
        int j2 = start + 2 < end ? start + 2 : lastj;
        int j3 = start + 3 < end ? start + 3 : lastj;
        int2 e0 = csr[start];
        int2 e1 = csr[j1];
        int2 e2 = csr[j2];
        int2 e3 = csr[j3];
        float w0 = __int_as_float(e0.y);
        float w1 = (deg > 1) ? __int_as_float(e1.y) : 0.f;
        float w2 = (deg > 2) ? __int_as_float(e2.y) : 0.f;
        float w3 = (deg > 3) ? __int_as_float(e3.y) : 0.f;
        us8 v0 = xin[(ll)e0.x * 8 + fl];
        us8 v1 = xin[(ll)e1.x * 8 + fl];
        us8 v2 = xin[(ll)e2.x * 8 + fl];
        us8 v3 = xin[(ll)e3.x * 8 + fl];
        fma8(s, w0, v0);
        fma8(s, w1, v1);
        fma8(s, w2, v2);
        fma8(s, w3, v3);
        int j = start + 4;
        for (; j + 1 < end; j += 2) {
            int2 a = csr[j];
            int2 b = csr[j + 1];
            us8 va = xin[(ll)a.x * 8 + fl];
            us8 vb = xin[(ll)b.x * 8 + fl];
            fma8(s, __int_as_float(a.y), va);
            fma8(s, __int_as_float(b.y), vb);
        }
        if (j < end) {
            int2 a = csr[j];
            us8 va = xin[(ll)a.x * 8 + fl];
            fma8(s, __int_as_float(a.y), va);
        }
    }
    return s;
}

// Layer 1: x1 = A x0 (bf16 in/out).
__global__ void k_prop(const us8* __restrict__ xin,
                       const int* __restrict__ rowptr,
                       const int2* __restrict__ csr,
                       us8* __restrict__ xout) {
    int wave = (blockIdx.x * blockDim.x + threadIdx.x) >> 6;
    int lane = threadIdx.x & 63;
    int sub = lane >> 3;
    int fl  = lane & 7;
    int nwaves = (gridDim.x * blockDim.x) >> 6;
    for (int nb = wave * 8; nb < N_NODES; nb += nwaves * 8) {
        int n = nb + sub;                      // N_NODES % 8 == 0
        f8 s = gather8(xin, rowptr, csr, n, fl);
        us8 o;
        #pragma unroll
        for (int k = 0; k < 8; ++k) o[k] = f2bf(s[k]);
        xout[(ll)n * 8 + fl] = o;
    }
}

// Layer 2 + partial combine: x2 = A x1; p012 = bf16(x0[n] + x1[n] + x2_fp32).
// p012 OVERWRITES the x01b buffer in place (same element, same thread —
// race-free), so no extra memory and the store hits just-read L3 lines.
__global__ void k_prop2p(us8* x01b,                       // in: x0b, out: p012
                         const us8* __restrict__ x1b,
                         const int* __restrict__ rowptr,
                         const int2* __restrict__ csr,
                         us8* __restrict__ x2b) {
    int wave = (blockIdx.x * blockDim.x + threadIdx.x) >> 6;
    int lane = threadIdx.x & 63;
    int sub = lane >> 3;
    int fl  = lane & 7;
    int nwaves = (gridDim.x * blockDim.x) >> 6;
    for (int nb = wave * 8; nb < N_NODES; nb += nwaves * 8) {
        int n = nb + sub;
        f8 s = gather8(x1b, rowptr, csr, n, fl);   // x2 (fp32, unrounded)
        ll idx8 = (ll)n * 8 + fl;
        us8 o;
        #pragma unroll
        for (int k = 0; k < 8; ++k) o[k] = f2bf(s[k]);
        x2b[idx8] = o;
        us8 x0v = x01b[idx8];
        us8 x1v = x1b[idx8];
        us8 p;
        #pragma unroll
        for (int k = 0; k < 8; ++k)
            p[k] = f2bf(bf2f(x0v[k]) + bf2f(x1v[k]) + s[k]);
        x01b[idx8] = p;
    }
}

// Final: x3 = A x2 (gather from L3-hot x2b); acc = 0.25*(p012 + x3) fp32.
__global__ void k_final(const us8* __restrict__ p012b,
                        const us8* __restrict__ x2b,
                        const int* __restrict__ rowptr,
                        const int2* __restrict__ csr,
                        f4* __restrict__ acc) {
    int wave = (blockIdx.x * blockDim.x + threadIdx.x) >> 6;
    int lane = threadIdx.x & 63;
    int sub = lane >> 3;
    int fl  = lane & 7;
    int nwaves = (gridDim.x * blockDim.x) >> 6;
    for (int nb = wave * 8; nb < N_NODES; nb += nwaves * 8) {
        int n = nb + sub;
        f8 s = gather8(x2b, rowptr, csr, n, fl);
        ll idx8 = (ll)n * 8 + fl;
        us8 pv = p012b[idx8];
        f4 rlo, rhi;
        #pragma unroll
        for (int k = 0; k < 4; ++k) {
            rlo[k] = 0.25f * (bf2f(pv[k]) + s[k]);
            rhi[k] = 0.25f * (bf2f(pv[k + 4]) + s[k + 4]);
        }
        f4* arow = acc + (ll)n * 16;
        __builtin_nontemporal_store(rlo, &arow[fl * 2]);
        __builtin_nontemporal_store(rhi, &arow[fl * 2 + 1]);
    }
}

// ---------------------------------------------------------------------------
// Fallback (round-1 atomic path) in case ws is too small.
// ---------------------------------------------------------------------------

__global__ void fb_init(const float* __restrict__ user_w,
                        const float* __restrict__ item_w,
                        float* __restrict__ acc, float* __restrict__ xcur) {
    const ll total4 = (ll)N_NODES * EMB_DIM / 4;
    const ll user4 = (ll)N_USERS * EMB_DIM / 4;
    const float4* uw = (const float4*)user_w;
    const float4* iw = (const float4*)item_w;
    float4* a4 = (float4*)acc;
    float4* x4 = (float4*)xcur;
    ll stride = (ll)gridDim.x * blockDim.x;
    for (ll i = (ll)blockIdx.x * blockDim.x + threadIdx.x; i < total4; i += stride) {
        float4 v = (i < user4) ? uw[i] : iw[i - user4];
        x4[i] = v;
        a4[i] = make_float4(0.25f * v.x, 0.25f * v.y, 0.25f * v.z, 0.25f * v.w);
    }
}
__global__ void fb_zero(float* __restrict__ p) {
    const ll total4 = (ll)N_NODES * EMB_DIM / 4;
    float4* p4 = (float4*)p;
    ll stride = (ll)gridDim.x * blockDim.x;
    float4 z = make_float4(0.f, 0.f, 0.f, 0.f);
    for (ll i = (ll)blockIdx.x * blockDim.x + threadIdx.x; i < total4; i += stride)
        p4[i] = z;
}
__global__ void fb_scatter(const float* __restrict__ xcur, const int* __restrict__ src,
                           const int* __restrict__ dst, const float* __restrict__ w,
                           float* __restrict__ xnext) {
    const int gpb = blockDim.x >> 6;
    const int d = threadIdx.x & 63;
    int eg = blockIdx.x * gpb + (threadIdx.x >> 6);
    const int estride = gridDim.x * gpb;
    for (int e = eg; e < N_EDGES; e += estride) {
        int s = src[e]; int t = dst[e]; float wt = w[e];
        atomicAdd(&xnext[(ll)t * EMB_DIM + d], xcur[(ll)s * EMB_DIM + d] * wt);
    }
}
__global__ void fb_accadd(const float* __restrict__ xn, float* __restrict__ acc) {
    const ll total4 = (ll)N_NODES * EMB_DIM / 4;
    const float4* x4 = (const float4*)xn;
    float4* a4 = (float4*)acc;
    ll stride = (ll)gridDim.x * blockDim.x;
    for (ll i = (ll)blockIdx.x * blockDim.x + threadIdx.x; i < total4; i += stride) {
        float4 v = x4[i]; float4 a = a4[i];
        a.x += 0.25f * v.x; a.y += 0.25f * v.y;
        a.z += 0.25f * v.z; a.w += 0.25f * v.w;
        a4[i] = a;
    }
}

// ---------------------------------------------------------------------------

extern "C" void kernel_launch(void* const* d_in, const int* in_sizes, int n_in,
                              void* d_out, int out_size, void* d_ws, size_t ws_size,
                              hipStream_t stream) {
    const float* user_w = (const float*)d_in[0];
    const float* item_w = (const float*)d_in[1];
    const int*   eidx   = (const int*)d_in[2];     // [2, N_EDGES] int32
    const float* ew     = (const float*)d_in[3];   // [N_EDGES]
    const int* src = eidx;
    const int* dst = eidx + N_EDGES;

    const size_t xb_bf = (size_t)N_NODES * EMB_DIM * 2;          // 64 MB each
    size_t off = 0;
    size_t x0_off     = off;   off += xb_bf;
    size_t x1_off     = off;   off += xb_bf;
    size_t x2_off     = off;   off += xb_bf;
    size_t stage_off  = off;   off += (size_t)NBUCK * BUCK_CAP * 8;   // ~12 MB
    size_t csr_off    = off;   off += (size_t)N_EDGES * 8;            // 9.6 MB
    size_t rowptr_off = off;   off += (size_t)(N_NODES + 1) * 4;      // 2 MB
    size_t gcur_off   = off;   off += 1024;
    size_t bbase_off  = off;   off += 1024;
    const size_t need = off;

    const int blk = 256;

    if (ws_size >= need) {
        us8*   x0b   = (us8*)((char*)d_ws + x0_off);   // becomes p012 in prop2
        us8*   x1b   = (us8*)((char*)d_ws + x1_off);
        us8*   x2b   = (us8*)((char*)d_ws + x2_off);
        uint2* stage = (uint2*)((char*)d_ws + stage_off);
        int2*  csr   = (int2*)((char*)d_ws + csr_off);
        int*   rowptr = (int*)((char*)d_ws + rowptr_off);
        int*   gcur   = (int*)((char*)d_ws + gcur_off);
        int*   bbase  = (int*)((char*)d_ws + bbase_off);
        f4*    acc    = (f4*)d_out;
        const f4* u4 = (const f4*)user_w;
        const f4* i4 = (const f4*)item_w;

        // --- CSR build + x0->bf16 conversion (fused/overlapped) ---
        k_init<<<1, 256, 0, stream>>>(gcur);
        k_bsort_conv<<<NB_SORT + NB_CONV, blk, 0, stream>>>(src, dst, ew, gcur,
                                                            stage, u4, i4, x0b);
        k_bscan<<<1, 256, 0, stream>>>(gcur, bbase, rowptr);
        k_place2<<<NBUCK, blk, 0, stream>>>(stage, gcur, bbase, rowptr, csr);

        // --- layers ---
        const int grid_l = 4096;
        k_prop<<<grid_l, blk, 0, stream>>>(x0b, rowptr, csr, x1b);
        k_prop2p<<<grid_l, blk, 0, stream>>>(x0b, x1b, rowptr, csr, x2b);
        k_final<<<grid_l, blk, 0, stream>>>(x0b, x2b, rowptr, csr, acc);
    } else {
        float* acc = (float*)d_out;
        float* xcur = (float*)d_ws;
        float* xnext = xcur + (ll)N_NODES * EMB_DIM;
        fb_init<<<2048, blk, 0, stream>>>(user_w, item_w, acc, xcur);
        for (int layer = 0; layer < 3; ++layer) {
            fb_zero<<<2048, blk, 0, stream>>>(xnext);
            fb_scatter<<<4096, blk, 0, stream>>>(xcur, src, dst, ew, xnext);
            fb_accadd<<<2048, blk, 0, stream>>>(xnext, acc);
            float* tmp = xcur; xcur = xnext; xnext = tmp;
        }
    }
}

// Round 12
// 223.932 us; speedup vs baseline: 1.0557x; 1.0557x over previous
//
#include <hip/hip_runtime.h>

#define N_USERS 100000
#define N_ITEMS 400000
#define N_NODES 500000
#define EMB_DIM 64
#define N_EDGES 1200000

#define BUCK_SHIFT 11
#define BUCK_NODES 2048                      // nodes per bucket
#define NBUCK 245                            // ceil(500000/2048)
#define BUCK_CAP 6144                        // >= max bucket count (mean ~4915, +17 sigma)
#define CHUNK 4096                           // edges per bsort block
#define NB_SORT 293                          // ceil(N_EDGES/CHUNK)
#define NB_CONV 1024                         // conv blocks appended to bsort grid

typedef long long ll;
typedef float f4 __attribute__((ext_vector_type(4)));
typedef float f8 __attribute__((ext_vector_type(8)));
typedef unsigned short u16;
typedef u16 us8 __attribute__((ext_vector_type(8)));   // 16 B (8 bf16)

__device__ __forceinline__ u16 f2bf(float f) {
    unsigned u = __float_as_uint(f);
    u += 0x7FFF + ((u >> 16) & 1);          // round-to-nearest-even
    return (u16)(u >> 16);
}
__device__ __forceinline__ float bf2f(u16 h) {
    return __uint_as_float(((unsigned)h) << 16);
}
__device__ __forceinline__ void fma8(f8& s, float w, us8 v) {
    #pragma unroll
    for (int k = 0; k < 8; ++k) s[k] += w * bf2f(v[k]);
}

// ---------------------------------------------------------------------------
// CSR build, locality-staged. bsort fused with x0->bf16 conversion.
// ---------------------------------------------------------------------------

__global__ void k_init(int* __restrict__ gcur) {
    if (threadIdx.x < 256) gcur[threadIdx.x] = 0;
}

__global__ void k_bsort_conv(const int* __restrict__ src, const int* __restrict__ dst,
                             const float* __restrict__ w,
                             int* __restrict__ gcur, uint2* __restrict__ stage,
                             const f4* __restrict__ u4, const f4* __restrict__ i4,
                             us8* __restrict__ x0b) {
    __shared__ int lhist[256];
    __shared__ int gbase_s[256];
    __shared__ int lcur[256];
    int tid = threadIdx.x;

    if (blockIdx.x >= NB_SORT) {
        // ---- conv portion: x0 fp32 -> bf16, streaming ----
        const int total = N_NODES * 8;       // us8 slots
        const int user8 = N_USERS * 8;
        int i0 = (blockIdx.x - NB_SORT) * 256 + tid;
        int stride = NB_CONV * 256;
        for (int i = i0; i < total; i += stride) {
            const f4* p = (i < user8) ? (u4 + (ll)i * 2) : (i4 + (ll)(i - user8) * 2);
            f4 lo = __builtin_nontemporal_load(p);
            f4 hi = __builtin_nontemporal_load(p + 1);
            us8 o;
            #pragma unroll
            for (int k = 0; k < 4; ++k) { o[k] = f2bf(lo[k]); o[k + 4] = f2bf(hi[k]); }
            x0b[i] = o;
        }
        return;
    }

    // ---- bsort portion ----
    lhist[tid] = 0;
    __syncthreads();
    int c0 = blockIdx.x * CHUNK;
    int c1 = c0 + CHUNK < N_EDGES ? c0 + CHUNK : N_EDGES;
    #pragma unroll
    for (int r = 0; r < CHUNK / 256; ++r) {
        int e = c0 + r * 256 + tid;
        if (e < c1) atomicAdd(&lhist[dst[e] >> BUCK_SHIFT], 1);
    }
    __syncthreads();
    if (tid < NBUCK) {
        gbase_s[tid] = atomicAdd(&gcur[tid], lhist[tid]);
        lcur[tid] = 0;
    }
    __syncthreads();
    #pragma unroll
    for (int r = 0; r < CHUNK / 256; ++r) {
        int e = c0 + r * 256 + tid;
        if (e < c1) {
            int s = src[e];
            int d = dst[e];
            float wt = w[e];
            int b = d >> BUCK_SHIFT;
            int k = atomicAdd(&lcur[b], 1);
            ll idx = (ll)b * BUCK_CAP + gbase_s[b] + k;
            stage[idx] = make_uint2((unsigned)s | ((unsigned)(d & (BUCK_NODES - 1)) << 19),
                                    __float_as_uint(wt));
        }
    }
}

// Per-bucket: redundant in-block bucket-scan -> LDS node histogram -> node scan
// -> rowptr write -> place into CSR. (k_bscan folded in: each block scans the
// 245 bucket totals itself — 245 L2-hit ints, ~1 us amortized, one less launch.)
__global__ void k_place2(const uint2* __restrict__ stage, const int* __restrict__ gcur,
                         int* __restrict__ rowptr, int2* __restrict__ csr) {
    __shared__ int lh[BUCK_NODES];
    __shared__ int tsum[256];
    int b = blockIdx.x;
    int tid = threadIdx.x;

    // --- bucket-base scan (redundant per block) ---
    int gv = (tid < NBUCK) ? gcur[tid] : 0;
    tsum[tid] = gv;
    __syncthreads();
    for (int off = 1; off < 256; off <<= 1) {
        int x = (tid >= off) ? tsum[tid - off] : 0;
        __syncthreads();
        tsum[tid] += x;
        __syncthreads();
    }
    int cnt = gcur[b];
    int bbase = tsum[b] - cnt;                // exclusive prefix for bucket b
    __syncthreads();

    // --- node histogram ---
    #pragma unroll
    for (int r = 0; r < BUCK_NODES / 256; ++r) lh[r * 256 + tid] = 0;
    __syncthreads();
    const uint2* sb = stage + (ll)b * BUCK_CAP;
    for (int i = tid; i < cnt; i += 256)
        atomicAdd(&lh[(sb[i].x >> 19) & (BUCK_NODES - 1)], 1);
    __syncthreads();

    // --- node scan: thread t owns lh[t*8 .. t*8+7] ---
    int base_t = tid * 8;
    int v[8];
    int s = 0;
    #pragma unroll
    for (int k = 0; k < 8; ++k) { v[k] = lh[base_t + k]; s += v[k]; }
    tsum[tid] = s;
    __syncthreads();
    for (int off = 1; off < 256; off <<= 1) {
        int x = (tid >= off) ? tsum[tid - off] : 0;
        __syncthreads();
        tsum[tid] += x;
        __syncthreads();
    }
    int run = bbase + tsum[tid] - s;          // absolute exclusive prefix
    int nbase = b * BUCK_NODES;
    #pragma unroll
    for (int k = 0; k < 8; ++k) {
        int i = base_t + k;
        int n = nbase + i;
        if (n < N_NODES) rowptr[n] = run;
        lh[i] = run;                          // absolute cursor
        run += v[k];
    }
    if (b == 0 && tid == 0) rowptr[N_NODES] = N_EDGES;
    __syncthreads();

    // --- place ---
    for (int i = tid; i < cnt; i += 256) {
        uint2 e = sb[i];
        int ldst = (e.x >> 19) & (BUCK_NODES - 1);
        int pos = atomicAdd(&lh[ldst], 1);
        csr[pos] = make_int2((int)(e.x & 0x7FFFF), (int)e.y);
    }
}

// ---------------------------------------------------------------------------
// Propagation: 8 nodes/wave, 8 lanes x bf16x8 per node; batch-of-4 gathers.
// ---------------------------------------------------------------------------

__device__ __forceinline__ f8 gather8(const us8* __restrict__ xin,
                                      const int* __restrict__ rowptr,
                                      const int2* __restrict__ csr,
                                      int n, int fl) {
    int start = rowptr[n];
    int end   = rowptr[n + 1];
    int deg = end - start;
    f8 s = {0.f, 0.f, 0.f, 0.f, 0.f, 0.f, 0.f, 0.f};
    if (deg > 0) {
        int lastj = end - 1;
        int j1 = start + 1 < end ? start + 1 : lastj;
        int j2 = start + 2 < end ? start + 2 : lastj;
        int j3 = start + 3 < end ? start + 3 : lastj;
        int2 e0 = csr[start];
        int2 e1 = csr[j1];
        int2 e2 = csr[j2];
        int2 e3 = csr[j3];
        float w0 = __int_as_float(e0.y);
        float w1 = (deg > 1) ? __int_as_float(e1.y) : 0.f;
        float w2 = (deg > 2) ? __int_as_float(e2.y) : 0.f;
        float w3 = (deg > 3) ? __int_as_float(e3.y) : 0.f;
        us8 v0 = xin[(ll)e0.x * 8 + fl];
        us8 v1 = xin[(ll)e1.x * 8 + fl];
        us8 v2 = xin[(ll)e2.x * 8 + fl];
        us8 v3 = xin[(ll)e3.x * 8 + fl];
        fma8(s, w0, v0);
        fma8(s, w1, v1);
        fma8(s, w2, v2);
        fma8(s, w3, v3);
        int j = start + 4;
        for (; j + 1 < end; j += 2) {
            int2 a = csr[j];
            int2 b = csr[j + 1];
            us8 va = xin[(ll)a.x * 8 + fl];
            us8 vb = xin[(ll)b.x * 8 + fl];
            fma8(s, __int_as_float(a.y), va);
            fma8(s, __int_as_float(b.y), vb);
        }
        if (j < end) {
            int2 a = csr[j];
            us8 va = xin[(ll)a.x * 8 + fl];
            fma8(s, __int_as_float(a.y), va);
        }
    }
    return s;
}

// Generic layer: xout = A xin (both bf16).
__global__ void k_prop(const us8* __restrict__ xin,
                       const int* __restrict__ rowptr,
                       const int2* __restrict__ csr,
                       us8* __restrict__ xout) {
    int wave = (blockIdx.x * blockDim.x + threadIdx.x) >> 6;
    int lane = threadIdx.x & 63;
    int sub = lane >> 3;
    int fl  = lane & 7;
    int nwaves = (gridDim.x * blockDim.x) >> 6;
    for (int nb = wave * 8; nb < N_NODES; nb += nwaves * 8) {
        int n = nb + sub;                      // N_NODES % 8 == 0
        f8 s = gather8(xin, rowptr, csr, n, fl);
        us8 o;
        #pragma unroll
        for (int k = 0; k < 8; ++k) o[k] = f2bf(s[k]);
        xout[(ll)n * 8 + fl] = o;
    }
}

// Final: gathers x3 from bf16 x2; acc = 0.25*(x0 + x1 + x2 + x3) in fp32.
// Single write of acc; x0/x1 reads non-temporal (single-use streams).
__global__ void k_final(const us8* __restrict__ x0b,
                        const us8* __restrict__ x1b, const us8* __restrict__ x2b,
                        const int* __restrict__ rowptr,
                        const int2* __restrict__ csr,
                        f4* __restrict__ acc) {
    int wave = (blockIdx.x * blockDim.x + threadIdx.x) >> 6;
    int lane = threadIdx.x & 63;
    int sub = lane >> 3;
    int fl  = lane & 7;
    int nwaves = (gridDim.x * blockDim.x) >> 6;
    for (int nb = wave * 8; nb < N_NODES; nb += nwaves * 8) {
        int n = nb + sub;
        f8 s = gather8(x2b, rowptr, csr, n, fl);
        ll idx8 = (ll)n * 8 + fl;
        us8 x0v = __builtin_nontemporal_load(&x0b[idx8]);
        us8 x1v = __builtin_nontemporal_load(&x1b[idx8]);
        us8 x2v = x2b[idx8];
        f4 rlo, rhi;
        #pragma unroll
        for (int k = 0; k < 4; ++k)
            rlo[k] = 0.25f * (bf2f(x0v[k]) + bf2f(x1v[k]) + bf2f(x2v[k]) + s[k]);
        #pragma unroll
        for (int k = 0; k < 4; ++k)
            rhi[k] = 0.25f * (bf2f(x0v[k + 4]) + bf2f(x1v[k + 4]) + bf2f(x2v[k + 4]) + s[k + 4]);
        f4* arow = acc + (ll)n * 16;
        __builtin_nontemporal_store(rlo, &arow[fl * 2]);
        __builtin_nontemporal_store(rhi, &arow[fl * 2 + 1]);
    }
}

// ---------------------------------------------------------------------------
// Fallback (round-1 atomic path) in case ws is too small.
// ---------------------------------------------------------------------------

__global__ void fb_init(const float* __restrict__ user_w,
                        const float* __restrict__ item_w,
                        float* __restrict__ acc, float* __restrict__ xcur) {
    const ll total4 = (ll)N_NODES * EMB_DIM / 4;
    const ll user4 = (ll)N_USERS * EMB_DIM / 4;
    const float4* uw = (const float4*)user_w;
    const float4* iw = (const float4*)item_w;
    float4* a4 = (float4*)acc;
    float4* x4 = (float4*)xcur;
    ll stride = (ll)gridDim.x * blockDim.x;
    for (ll i = (ll)blockIdx.x * blockDim.x + threadIdx.x; i < total4; i += stride) {
        float4 v = (i < user4) ? uw[i] : iw[i - user4];
        x4[i] = v;
        a4[i] = make_float4(0.25f * v.x, 0.25f * v.y, 0.25f * v.z, 0.25f * v.w);
    }
}
__global__ void fb_zero(float* __restrict__ p) {
    const ll total4 = (ll)N_NODES * EMB_DIM / 4;
    float4* p4 = (float4*)p;
    ll stride = (ll)gridDim.x * blockDim.x;
    float4 z = make_float4(0.f, 0.f, 0.f, 0.f);
    for (ll i = (ll)blockIdx.x * blockDim.x + threadIdx.x; i < total4; i += stride)
        p4[i] = z;
}
__global__ void fb_scatter(const float* __restrict__ xcur, const int* __restrict__ src,
                           const int* __restrict__ dst, const float* __restrict__ w,
                           float* __restrict__ xnext) {
    const int gpb = blockDim.x >> 6;
    const int d = threadIdx.x & 63;
    int eg = blockIdx.x * gpb + (threadIdx.x >> 6);
    const int estride = gridDim.x * gpb;
    for (int e = eg; e < N_EDGES; e += estride) {
        int s = src[e]; int t = dst[e]; float wt = w[e];
        atomicAdd(&xnext[(ll)t * EMB_DIM + d], xcur[(ll)s * EMB_DIM + d] * wt);
    }
}
__global__ void fb_accadd(const float* __restrict__ xn, float* __restrict__ acc) {
    const ll total4 = (ll)N_NODES * EMB_DIM / 4;
    const float4* x4 = (const float4*)xn;
    float4* a4 = (float4*)acc;
    ll stride = (ll)gridDim.x * blockDim.x;
    for (ll i = (ll)blockIdx.x * blockDim.x + threadIdx.x; i < total4; i += stride) {
        float4 v = x4[i]; float4 a = a4[i];
        a.x += 0.25f * v.x; a.y += 0.25f * v.y;
        a.z += 0.25f * v.z; a.w += 0.25f * v.w;
        a4[i] = a;
    }
}

// ---------------------------------------------------------------------------

extern "C" void kernel_launch(void* const* d_in, const int* in_sizes, int n_in,
                              void* d_out, int out_size, void* d_ws, size_t ws_size,
                              hipStream_t stream) {
    const float* user_w = (const float*)d_in[0];
    const float* item_w = (const float*)d_in[1];
    const int*   eidx   = (const int*)d_in[2];     // [2, N_EDGES] int32
    const float* ew     = (const float*)d_in[3];   // [N_EDGES]
    const int* src = eidx;
    const int* dst = eidx + N_EDGES;

    const size_t xb_bf = (size_t)N_NODES * EMB_DIM * 2;          // 64 MB each
    size_t off = 0;
    size_t x0_off     = off;   off += xb_bf;
    size_t x1_off     = off;   off += xb_bf;
    size_t x2_off     = off;   off += xb_bf;
    size_t stage_off  = off;   off += (size_t)NBUCK * BUCK_CAP * 8;   // ~12 MB
    size_t csr_off    = off;   off += (size_t)N_EDGES * 8;            // 9.6 MB
    size_t rowptr_off = off;   off += (size_t)(N_NODES + 1) * 4;      // 2 MB
    size_t gcur_off   = off;   off += 1024;
    const size_t need = off;

    const int blk = 256;

    if (ws_size >= need) {
        us8*   x0b   = (us8*)((char*)d_ws + x0_off);
        us8*   x1b   = (us8*)((char*)d_ws + x1_off);
        us8*   x2b   = (us8*)((char*)d_ws + x2_off);
        uint2* stage = (uint2*)((char*)d_ws + stage_off);
        int2*  csr   = (int2*)((char*)d_ws + csr_off);
        int*   rowptr = (int*)((char*)d_ws + rowptr_off);
        int*   gcur   = (int*)((char*)d_ws + gcur_off);
        f4*    acc    = (f4*)d_out;
        const f4* u4 = (const f4*)user_w;
        const f4* i4 = (const f4*)item_w;

        // --- CSR build + x0->bf16 conversion (fused/overlapped) ---
        k_init<<<1, 256, 0, stream>>>(gcur);
        k_bsort_conv<<<NB_SORT + NB_CONV, blk, 0, stream>>>(src, dst, ew, gcur,
                                                            stage, u4, i4, x0b);
        k_place2<<<NBUCK, blk, 0, stream>>>(stage, gcur, rowptr, csr);

        // --- layers ---
        const int grid_l = 4096;
        k_prop<<<grid_l, blk, 0, stream>>>(x0b, rowptr, csr, x1b);
        k_prop<<<grid_l, blk, 0, stream>>>(x1b, rowptr, csr, x2b);
        k_final<<<grid_l, blk, 0, stream>>>(x0b, x1b, x2b, rowptr, csr, acc);
    } else {
        float* acc = (float*)d_out;
        float* xcur = (float*)d_ws;
        float* xnext = xcur + (ll)N_NODES * EMB_DIM;
        fb_init<<<2048, blk, 0, stream>>>(user_w, item_w, acc, xcur);
        for (int layer = 0; layer < 3; ++layer) {
            fb_zero<<<2048, blk, 0, stream>>>(xnext);
            fb_scatter<<<4096, blk, 0, stream>>>(xcur, src, dst, ew, xnext);
            fb_accadd<<<2048, blk, 0, stream>>>(xnext, acc);
            float* tmp = xcur; xcur = xnext; xnext = tmp;
        }
    }
}